// Round 1
// baseline (573.571 us; speedup 1.0000x reference)
//
#include <hip/hip_runtime.h>
#include <math.h>

#define BATCH 512
#define DIM 512
#define NCLASS 100000
#define BN 64
#define NBLK ((NCLASS + BN - 1) / BN) /* 1563 */
#define GRID 256
#define S_SCALE 30.0f
#define COSM 0.8775825618903728f
#define SINM 0.4794255386042030f

typedef unsigned short u16;
typedef __attribute__((ext_vector_type(8))) short short8;
typedef __attribute__((ext_vector_type(4))) float floatx4;

// ws layout (bytes):
//   [0, 524288)            xn bf16 [512][512]
//   [524288, 526336)       tlogit float[512]
//   [526336, 528384)       nll    float[512]
//   [528384, +512*NBLK*4)  partials [512][NBLK]  (TRANSPOSED: row = batch m, coalesced reduce)

__device__ __forceinline__ u16 f2bf(float f) {
    union { float f; unsigned int u; } v;
    v.f = f;
    unsigned int u = v.u;
    u += 0x7fffu + ((u >> 16) & 1u);   // round-to-nearest-even
    return (u16)(u >> 16);
}

// ---------------- Kernel 1: normalize x rows -> bf16 ----------------
__global__ void xnorm_kernel(const float* __restrict__ x, u16* __restrict__ xn) {
    const int row = blockIdx.x;
    const int t = threadIdx.x; // 64 threads = 1 wave
    const floatx4* xr = (const floatx4*)(x + (size_t)row * DIM);
    floatx4 a = xr[t];
    floatx4 b = xr[t + 64];
    float ss = a[0]*a[0] + a[1]*a[1] + a[2]*a[2] + a[3]*a[3]
             + b[0]*b[0] + b[1]*b[1] + b[2]*b[2] + b[3]*b[3];
#pragma unroll
    for (int d = 1; d < 64; d <<= 1) ss += __shfl_xor(ss, d);
    const float rn = 1.0f / fmaxf(sqrtf(ss), 1e-12f);
    ushort4 ua, ub;
    ua.x = f2bf(a[0]*rn); ua.y = f2bf(a[1]*rn); ua.z = f2bf(a[2]*rn); ua.w = f2bf(a[3]*rn);
    ub.x = f2bf(b[0]*rn); ub.y = f2bf(b[1]*rn); ub.z = f2bf(b[2]*rn); ub.w = f2bf(b[3]*rn);
    u16* orow = xn + (size_t)row * DIM;
    *(ushort4*)(orow + 4*t)       = ua;
    *(ushort4*)(orow + 256 + 4*t) = ub;
}

// ---------------- staging write: raw bf16 tile + per-row 1/norm ----------------
// Post-scale scheme: LDS holds bf16(raw w); 1/||w|| (fp32 from raw values) is
// applied to accumulator COLUMNS in the epilogue. Removes the normalize-before-
// write dependency so staging pipelines with MFMA.
__device__ __forceinline__ void stage_write(const floatx4* v, u16* __restrict__ wbuf,
                                            float* __restrict__ rsbuf, int sr, int sq) {
    float ss = 0.f;
#pragma unroll
    for (int i = 0; i < 16; ++i)
        ss += v[i][0]*v[i][0] + v[i][1]*v[i][1] + v[i][2]*v[i][2] + v[i][3]*v[i][3];
    // reduce across the 8 threads of this row (lane bits 0..2)
    ss += __shfl_xor(ss, 1);
    ss += __shfl_xor(ss, 2);
    ss += __shfl_xor(ss, 4);
    if (sq == 0) rsbuf[sr] = 1.0f / fmaxf(sqrtf(ss), 1e-12f);
#pragma unroll
    for (int i = 0; i < 16; ++i) {
        const int col4 = sq + (i << 3);
        const int gp = (col4 >> 1) ^ (sr & 7);        // XOR-swizzled 16B granule
        const int off = sr * DIM + gp * 8 + (col4 & 1) * 4;
        ushort4 u;
        u.x = f2bf(v[i][0]); u.y = f2bf(v[i][1]);
        u.z = f2bf(v[i][2]); u.w = f2bf(v[i][3]);
        *(ushort4*)(&wbuf[off]) = u;
    }
}

// ---------------- one tile: MFMA + epilogue, with paced prefetch of next tile ----------------
template<bool PREF>
__device__ __forceinline__ void process_tile(
        const float* __restrict__ w, const u16* __restrict__ xn,
        float* __restrict__ partials, float* __restrict__ tlogit,
        const u16* __restrict__ wbc, u16* __restrict__ wbn,
        const float* __restrict__ rsc, float* __restrict__ rsn,
        const int* __restrict__ tgt, int tile,
        int mbase, int quad, int nin, int sr, int sq) {

    floatx4 v[16];
    const floatx4* wr = (const floatx4*)w;
    if (PREF) {
        // clamp instead of branch: last tile re-reads row 99999 harmlessly;
        // out-of-range columns are masked in the epilogue.
        const int cg = min((tile + GRID) * BN + sr, NCLASS - 1);
        wr = (const floatx4*)(w + (size_t)cg * DIM);
    }

    floatx4 acc[4][4];
#pragma unroll
    for (int mi = 0; mi < 4; ++mi)
#pragma unroll
        for (int ni = 0; ni < 4; ++ni) {
            acc[mi][ni][0] = 0.f; acc[mi][ni][1] = 0.f;
            acc[mi][ni][2] = 0.f; acc[mi][ni][3] = 0.f;
        }

    const u16* xbase = xn + (size_t)(mbase + nin) * DIM + quad * 8;

    // Fully unrolled K-loop; one W float4 issued per kk so the in-order vmcnt
    // never forces a bulk drain of the whole 131 KB prefetch at kk=0.
#pragma unroll
    for (int kk = 0; kk < 16; ++kk) {
        if (PREF) v[kk] = wr[sq + (kk << 3)];
        short8 a[4], b[4];
#pragma unroll
        for (int mi = 0; mi < 4; ++mi)
            a[mi] = *(const short8*)(xbase + (size_t)mi * 16 * DIM + kk * 32);
#pragma unroll
        for (int ni = 0; ni < 4; ++ni) {
            const int cl = ni * 16 + nin;
            const int gp = ((kk << 2) + quad) ^ (cl & 7);
            b[ni] = *(const short8*)(&wbc[cl * DIM + gp * 8]);
        }
#pragma unroll
        for (int mi = 0; mi < 4; ++mi)
#pragma unroll
            for (int ni = 0; ni < 4; ++ni)
                acc[mi][ni] = __builtin_amdgcn_mfma_f32_16x16x32_bf16(
                    a[mi], b[ni], acc[mi][ni], 0, 0, 0);
    }

    // ---- epilogue: post-scale by 1/||w||, arcface transform, per-row exp-sum ----
    // Runs on VALU while the prefetch stream drains.
    const int c0 = tile * BN;
    float rsl[4];
#pragma unroll
    for (int ni = 0; ni < 4; ++ni) rsl[ni] = rsc[ni * 16 + nin];

#pragma unroll
    for (int mi = 0; mi < 4; ++mi) {
#pragma unroll
        for (int reg = 0; reg < 4; ++reg) {
            const int m = mbase + mi * 16 + quad * 4 + reg;
            const int tg = tgt[mi * 4 + reg];
            float psum = 0.f;
#pragma unroll
            for (int ni = 0; ni < 4; ++ni) {
                const int c = c0 + ni * 16 + nin;
                if (c < NCLASS) {
                    const float cosv = acc[mi][ni][reg] * rsl[ni];
                    float lg;
                    if (c == tg) {
                        const float sine = sqrtf(fmaxf(1.f - cosv * cosv, 0.f));
                        float phi = cosv * COSM - sine * SINM;
                        if (!(cosv > 0.f)) phi = cosv;   // easy_margin
                        lg = S_SCALE * phi;
                        tlogit[m] = lg;
                    } else {
                        lg = S_SCALE * cosv;
                    }
                    psum += __expf(lg - S_SCALE);        // fixed shift S (logit <= S)
                }
            }
            psum += __shfl_xor(psum, 1);
            psum += __shfl_xor(psum, 2);
            psum += __shfl_xor(psum, 4);
            psum += __shfl_xor(psum, 8);
            if (nin == 0)
                partials[(size_t)m * NBLK + tile] = psum;   // transposed layout
        }
    }

    if (PREF) stage_write(v, wbn, rsn, sr, sq);
}

// ---------------- Kernel 2: persistent fused GEMM, double-buffered W staging ----------------
__global__ __launch_bounds__(512, 2) void arcface_main(
        const float* __restrict__ w, const u16* __restrict__ xn,
        const int* __restrict__ target, float* __restrict__ partials,
        float* __restrict__ tlogit) {
    __shared__ __align__(16) u16 wb[2][BN * DIM];   // 2 x 64 KB
    __shared__ float rs_s[2][BN];

    const int t = threadIdx.x;
    const int wave = t >> 6;
    const int lane = t & 63;
    const int quad = lane >> 4;
    const int nin  = lane & 15;
    const int mbase = wave * 64;
    const int sr = t >> 3;   // staging row 0..63
    const int sq = t & 7;    // 8 threads per row

    // targets for this thread's 16 output rows are tile-invariant: preload once
    int tgt[16];
#pragma unroll
    for (int mi = 0; mi < 4; ++mi)
#pragma unroll
        for (int reg = 0; reg < 4; ++reg)
            tgt[mi * 4 + reg] = target[mbase + mi * 16 + quad * 4 + reg];

    // ---- prologue: stage first tile into buf 0 ----
    {
        const int cg = min((int)blockIdx.x * BN + sr, NCLASS - 1);
        const floatx4* wr = (const floatx4*)(w + (size_t)cg * DIM);
        floatx4 v[16];
#pragma unroll
        for (int i = 0; i < 16; ++i) v[i] = wr[sq + (i << 3)];
        stage_write(v, wb[0], rs_s[0], sr, sq);
    }
    __syncthreads();

    int cur = 0;
    int tile = blockIdx.x;
    while (tile + GRID < NBLK) {
        process_tile<true>(w, xn, partials, tlogit,
                           wb[cur], wb[cur ^ 1], rs_s[cur], rs_s[cur ^ 1],
                           tgt, tile, mbase, quad, nin, sr, sq);
        __syncthreads();
        cur ^= 1;
        tile += GRID;
    }
    process_tile<false>(w, xn, partials, tlogit,
                        wb[cur], wb[cur ^ 1], rs_s[cur], rs_s[cur ^ 1],
                        tgt, tile, mbase, quad, nin, sr, sq);
}

// ---------------- Kernel 3a: per-row logsumexp + nll (coalesced rows now) ----------------
__global__ void reduce_lse(const float* __restrict__ partials,
                           const float* __restrict__ tlogit,
                           float* __restrict__ nll) {
    const int m = blockIdx.x;
    const int t = threadIdx.x; // 256
    const float* row = partials + (size_t)m * NBLK;
    float s = 0.f;
    for (int b = t; b < NBLK; b += 256) s += row[b];
#pragma unroll
    for (int d = 1; d < 64; d <<= 1) s += __shfl_xor(s, d);
    __shared__ float red[4];
    if ((t & 63) == 0) red[t >> 6] = s;
    __syncthreads();
    if (t == 0) {
        const float tot = red[0] + red[1] + red[2] + red[3];
        nll[m] = (logf(tot) + S_SCALE) - tlogit[m];
    }
}

// ---------------- Kernel 3b: mean ----------------
__global__ void reduce_mean(const float* __restrict__ nll, float* __restrict__ out) {
    const int t = threadIdx.x; // 512
    float s = nll[t];
#pragma unroll
    for (int d = 1; d < 64; d <<= 1) s += __shfl_xor(s, d);
    __shared__ float red[8];
    if ((t & 63) == 0) red[t >> 6] = s;
    __syncthreads();
    if (t == 0) {
        float tot = 0.f;
#pragma unroll
        for (int i = 0; i < 8; ++i) tot += red[i];
        out[0] = tot / (float)BATCH;
    }
}

extern "C" void kernel_launch(void* const* d_in, const int* in_sizes, int n_in,
                              void* d_out, int out_size, void* d_ws, size_t ws_size,
                              hipStream_t stream) {
    const float* x = (const float*)d_in[0];
    const float* w = (const float*)d_in[1];
    const int* target = (const int*)d_in[2];

    char* ws = (char*)d_ws;
    u16* xn        = (u16*)ws;
    float* tlogit  = (float*)(ws + 524288);
    float* nll     = (float*)(ws + 526336);
    float* partials= (float*)(ws + 528384);

    xnorm_kernel<<<BATCH, 64, 0, stream>>>(x, xn);
    arcface_main<<<GRID, 512, 0, stream>>>(w, xn, target, partials, tlogit);
    reduce_lse<<<BATCH, 256, 0, stream>>>(partials, tlogit, nll);
    reduce_mean<<<1, 512, 0, stream>>>(nll, (float*)d_out);
}

// Round 2
// 560.770 us; speedup vs baseline: 1.0228x; 1.0228x over previous
//
#include <hip/hip_runtime.h>
#include <math.h>

#define BATCH 512
#define DIM 512
#define NCLASS 100000
#define BN 64
#define NBLK ((NCLASS + BN - 1) / BN) /* 1563 */
#define GRID 256
#define S_SCALE 30.0f
#define COSM 0.8775825618903728f
#define SINM 0.4794255386042030f

typedef unsigned short u16;
typedef __attribute__((ext_vector_type(8))) short short8;
typedef __attribute__((ext_vector_type(4))) float floatx4;

// ws layout (bytes):
//   [0, 524288)            xn bf16 [512][512]
//   [524288, 526336)       tlogit float[512]
//   [526336, 528384)       nll    float[512]
//   [528384, +NBLK*512*4)  partials [NBLK][512]   (coalesced 2KB burst per tile)

__device__ __forceinline__ u16 f2bf(float f) {
    union { float f; unsigned int u; } v;
    v.f = f;
    unsigned int u = v.u;
    u += 0x7fffu + ((u >> 16) & 1u);   // round-to-nearest-even
    return (u16)(u >> 16);
}

// ---------------- Kernel 1: normalize x rows -> bf16 ----------------
__global__ void xnorm_kernel(const float* __restrict__ x, u16* __restrict__ xn) {
    const int row = blockIdx.x;
    const int t = threadIdx.x; // 64 threads = 1 wave
    const floatx4* xr = (const floatx4*)(x + (size_t)row * DIM);
    floatx4 a = xr[t];
    floatx4 b = xr[t + 64];
    float ss = a[0]*a[0] + a[1]*a[1] + a[2]*a[2] + a[3]*a[3]
             + b[0]*b[0] + b[1]*b[1] + b[2]*b[2] + b[3]*b[3];
#pragma unroll
    for (int d = 1; d < 64; d <<= 1) ss += __shfl_xor(ss, d);
    const float rn = 1.0f / fmaxf(sqrtf(ss), 1e-12f);
    ushort4 ua, ub;
    ua.x = f2bf(a[0]*rn); ua.y = f2bf(a[1]*rn); ua.z = f2bf(a[2]*rn); ua.w = f2bf(a[3]*rn);
    ub.x = f2bf(b[0]*rn); ub.y = f2bf(b[1]*rn); ub.z = f2bf(b[2]*rn); ub.w = f2bf(b[3]*rn);
    u16* orow = xn + (size_t)row * DIM;
    *(ushort4*)(orow + 4*t)       = ua;
    *(ushort4*)(orow + 256 + 4*t) = ub;
}

// ---------------- staging write: raw bf16 tile + per-row 1/norm ----------------
// Post-scale scheme: LDS holds bf16(raw w); 1/||w|| (fp32 from raw values) is
// applied to accumulator COLUMNS in the epilogue.
__device__ __forceinline__ void stage_write(const floatx4* v, u16* __restrict__ wbuf,
                                            float* __restrict__ rsbuf, int sr, int sq) {
    float ss = 0.f;
#pragma unroll
    for (int i = 0; i < 16; ++i)
        ss += v[i][0]*v[i][0] + v[i][1]*v[i][1] + v[i][2]*v[i][2] + v[i][3]*v[i][3];
    // reduce across the 8 threads of this row (lane bits 0..2)
    ss += __shfl_xor(ss, 1);
    ss += __shfl_xor(ss, 2);
    ss += __shfl_xor(ss, 4);
    if (sq == 0) rsbuf[sr] = 1.0f / fmaxf(sqrtf(ss), 1e-12f);
#pragma unroll
    for (int i = 0; i < 16; ++i) {
        const int col4 = sq + (i << 3);
        const int gp = (col4 >> 1) ^ (sr & 7);        // XOR-swizzled 16B granule
        const int off = sr * DIM + gp * 8 + (col4 & 1) * 4;
        ushort4 u;
        u.x = f2bf(v[i][0]); u.y = f2bf(v[i][1]);
        u.z = f2bf(v[i][2]); u.w = f2bf(v[i][3]);
        *(ushort4*)(&wbuf[off]) = u;
    }
}

// ---------------- one tile: MFMA + epilogue, with paced prefetch of next tile ----------------
template<bool PREF>
__device__ __forceinline__ void process_tile(
        const float* __restrict__ w, const u16* __restrict__ xn,
        float* __restrict__ partials, float* __restrict__ tlogit,
        const u16* __restrict__ wbc, u16* __restrict__ wbn,
        const float* __restrict__ rsc, float* __restrict__ rsn,
        const int* __restrict__ tgt, int tile,
        int mbase, int quad, int nin, int sr, int sq) {

    floatx4 v[16];
    const floatx4* wr = (const floatx4*)w;
    if (PREF) {
        // clamp instead of branch: last tile re-reads row 99999 harmlessly;
        // out-of-range columns are masked in the epilogue.
        const int cg = min((tile + GRID) * BN + sr, NCLASS - 1);
        wr = (const floatx4*)(w + (size_t)cg * DIM);
    }

    floatx4 acc[4][4];
#pragma unroll
    for (int mi = 0; mi < 4; ++mi)
#pragma unroll
        for (int ni = 0; ni < 4; ++ni) {
            acc[mi][ni][0] = 0.f; acc[mi][ni][1] = 0.f;
            acc[mi][ni][2] = 0.f; acc[mi][ni][3] = 0.f;
        }

    const u16* xbase = xn + (size_t)(mbase + nin) * DIM + quad * 8;

    // Fully unrolled K-loop; one W float4 per kk, issued AFTER the a-loads of
    // this kk so the MFMA's vmcnt wait on a[] only forces W loads issued >= 1
    // full iteration earlier (vmcnt drains in issue order).
#pragma unroll
    for (int kk = 0; kk < 16; ++kk) {
        short8 a[4], b[4];
#pragma unroll
        for (int mi = 0; mi < 4; ++mi)
            a[mi] = *(const short8*)(xbase + (size_t)mi * 16 * DIM + kk * 32);
        if (PREF) v[kk] = wr[sq + (kk << 3)];
#pragma unroll
        for (int ni = 0; ni < 4; ++ni) {
            const int cl = ni * 16 + nin;
            const int gp = ((kk << 2) + quad) ^ (cl & 7);
            b[ni] = *(const short8*)(&wbc[cl * DIM + gp * 8]);
        }
#pragma unroll
        for (int mi = 0; mi < 4; ++mi)
#pragma unroll
            for (int ni = 0; ni < 4; ++ni)
                acc[mi][ni] = __builtin_amdgcn_mfma_f32_16x16x32_bf16(
                    a[mi], b[ni], acc[mi][ni], 0, 0, 0);
    }

    // ---- epilogue: post-scale by 1/||w||, arcface transform, per-row exp-sum ----
    const int c0 = tile * BN;
    float rsl[4];
#pragma unroll
    for (int ni = 0; ni < 4; ++ni) rsl[ni] = rsc[ni * 16 + nin];

#pragma unroll
    for (int mi = 0; mi < 4; ++mi) {
#pragma unroll
        for (int reg = 0; reg < 4; ++reg) {
            const int m = mbase + mi * 16 + quad * 4 + reg;
            const int tg = tgt[mi * 4 + reg];
            float psum = 0.f;
#pragma unroll
            for (int ni = 0; ni < 4; ++ni) {
                const int c = c0 + ni * 16 + nin;
                if (c < NCLASS) {
                    const float cosv = acc[mi][ni][reg] * rsl[ni];
                    float lg;
                    if (c == tg) {
                        const float sine = sqrtf(fmaxf(1.f - cosv * cosv, 0.f));
                        float phi = cosv * COSM - sine * SINM;
                        if (!(cosv > 0.f)) phi = cosv;   // easy_margin
                        lg = S_SCALE * phi;
                        tlogit[m] = lg;
                    } else {
                        lg = S_SCALE * cosv;
                    }
                    psum += __expf(lg - S_SCALE);        // fixed shift S (logit <= S)
                }
            }
            psum += __shfl_xor(psum, 1);
            psum += __shfl_xor(psum, 2);
            psum += __shfl_xor(psum, 4);
            psum += __shfl_xor(psum, 8);
            if (nin == 0)
                partials[(size_t)tile * BATCH + m] = psum;   // coalesced per-tile burst
        }
    }

    if (PREF) stage_write(v, wbn, rsn, sr, sq);
}

// ---------------- Kernel 2: persistent fused GEMM, double-buffered W staging ----------------
__global__ __launch_bounds__(512, 2) void arcface_main(
        const float* __restrict__ w, const u16* __restrict__ xn,
        const int* __restrict__ target, float* __restrict__ partials,
        float* __restrict__ tlogit) {
    __shared__ __align__(16) u16 wb[2][BN * DIM];   // 2 x 64 KB
    __shared__ float rs_s[2][BN];

    const int t = threadIdx.x;
    const int wave = t >> 6;
    const int lane = t & 63;
    const int quad = lane >> 4;
    const int nin  = lane & 15;
    const int mbase = wave * 64;
    const int sr = t >> 3;   // staging row 0..63
    const int sq = t & 7;    // 8 threads per row

    // targets for this thread's 16 output rows are tile-invariant: preload once
    int tgt[16];
#pragma unroll
    for (int mi = 0; mi < 4; ++mi)
#pragma unroll
        for (int reg = 0; reg < 4; ++reg)
            tgt[mi * 4 + reg] = target[mbase + mi * 16 + quad * 4 + reg];

    // ---- prologue: stage first tile into buf 0 ----
    {
        const int cg = min((int)blockIdx.x * BN + sr, NCLASS - 1);
        const floatx4* wr = (const floatx4*)(w + (size_t)cg * DIM);
        floatx4 v[16];
#pragma unroll
        for (int i = 0; i < 16; ++i) v[i] = wr[sq + (i << 3)];
        stage_write(v, wb[0], rs_s[0], sr, sq);
    }
    __syncthreads();

    int cur = 0;
    int tile = blockIdx.x;
    while (tile + GRID < NBLK) {
        process_tile<true>(w, xn, partials, tlogit,
                           wb[cur], wb[cur ^ 1], rs_s[cur], rs_s[cur ^ 1],
                           tgt, tile, mbase, quad, nin, sr, sq);
        __syncthreads();
        cur ^= 1;
        tile += GRID;
    }
    process_tile<false>(w, xn, partials, tlogit,
                        wb[cur], wb[cur ^ 1], rs_s[cur], rs_s[cur ^ 1],
                        tgt, tile, mbase, quad, nin, sr, sq);
}

// ---------------- Kernel 3a: per-row logsumexp + nll ----------------
__global__ void reduce_lse(const float* __restrict__ partials,
                           const float* __restrict__ tlogit,
                           float* __restrict__ nll) {
    const int m = blockIdx.x;
    const int t = threadIdx.x; // 256
    float s = 0.f;
    for (int b = t; b < NBLK; b += 256) s += partials[(size_t)b * BATCH + m];
#pragma unroll
    for (int d = 1; d < 64; d <<= 1) s += __shfl_xor(s, d);
    __shared__ float red[4];
    if ((t & 63) == 0) red[t >> 6] = s;
    __syncthreads();
    if (t == 0) {
        const float tot = red[0] + red[1] + red[2] + red[3];
        nll[m] = (logf(tot) + S_SCALE) - tlogit[m];
    }
}

// ---------------- Kernel 3b: mean ----------------
__global__ void reduce_mean(const float* __restrict__ nll, float* __restrict__ out) {
    const int t = threadIdx.x; // 512
    float s = nll[t];
#pragma unroll
    for (int d = 1; d < 64; d <<= 1) s += __shfl_xor(s, d);
    __shared__ float red[8];
    if ((t & 63) == 0) red[t >> 6] = s;
    __syncthreads();
    if (t == 0) {
        float tot = 0.f;
#pragma unroll
        for (int i = 0; i < 8; ++i) tot += red[i];
        out[0] = tot / (float)BATCH;
    }
}

extern "C" void kernel_launch(void* const* d_in, const int* in_sizes, int n_in,
                              void* d_out, int out_size, void* d_ws, size_t ws_size,
                              hipStream_t stream) {
    const float* x = (const float*)d_in[0];
    const float* w = (const float*)d_in[1];
    const int* target = (const int*)d_in[2];

    char* ws = (char*)d_ws;
    u16* xn        = (u16*)ws;
    float* tlogit  = (float*)(ws + 524288);
    float* nll     = (float*)(ws + 526336);
    float* partials= (float*)(ws + 528384);

    xnorm_kernel<<<BATCH, 64, 0, stream>>>(x, xn);
    arcface_main<<<GRID, 512, 0, stream>>>(w, xn, target, partials, tlogit);
    reduce_lse<<<BATCH, 256, 0, stream>>>(partials, tlogit, nll);
    reduce_mean<<<1, 512, 0, stream>>>(nll, (float*)d_out);
}

// Round 3
// 531.283 us; speedup vs baseline: 1.0796x; 1.0555x over previous
//
#include <hip/hip_runtime.h>
#include <hip/hip_bf16.h>
#include <math.h>

#define BATCH 512
#define DIM 512
#define NCLASS 100000
#define BNB 256                      /* block tile cols */
#define NT 391                       /* ceil(100000/256) */
#define NSTREAM 64
#define GRID 256                     /* 4 M-groups x 64 streams */
#define S_SCALE 30.0f
#define COSM 0.8775825618903728f
#define SINM 0.4794255386042030f
#define LOG2E 1.44269504088896f

typedef unsigned short u16;
typedef __attribute__((ext_vector_type(8))) short short8;
typedef __attribute__((ext_vector_type(4))) float floatx4;
typedef __attribute__((ext_vector_type(16))) float floatx16;

// ws layout (bytes):
//   [0, 524288)         xn bf16 [512][512]
//   [524288, 655360)    partials [64 streams][512 rows] f32
//   [655360, 657408)    nll float[512]

__device__ __forceinline__ u16 f2bf(float f) {
    union { __hip_bfloat16 h; u16 u; } c;
    c.h = __float2bfloat16(f);       // RNE, native v_cvt on gfx950
    return c.u;
}
__device__ __forceinline__ float bf2f(u16 b) {
    union { float f; unsigned int u; } v;
    v.u = ((unsigned int)b) << 16;
    return v.f;
}

// ---------------- Kernel 1: normalize x rows -> bf16 ----------------
__global__ void xnorm_kernel(const float* __restrict__ x, u16* __restrict__ xn) {
    const int row = blockIdx.x;
    const int t = threadIdx.x; // 64 threads = 1 wave
    const floatx4* xr = (const floatx4*)(x + (size_t)row * DIM);
    floatx4 a = xr[t];
    floatx4 b = xr[t + 64];
    float ss = a[0]*a[0] + a[1]*a[1] + a[2]*a[2] + a[3]*a[3]
             + b[0]*b[0] + b[1]*b[1] + b[2]*b[2] + b[3]*b[3];
#pragma unroll
    for (int d = 1; d < 64; d <<= 1) ss += __shfl_xor(ss, d);
    const float rn = 1.0f / fmaxf(sqrtf(ss), 1e-12f);
    ushort4 ua, ub;
    ua.x = f2bf(a[0]*rn); ua.y = f2bf(a[1]*rn); ua.z = f2bf(a[2]*rn); ua.w = f2bf(a[3]*rn);
    ub.x = f2bf(b[0]*rn); ub.y = f2bf(b[1]*rn); ub.z = f2bf(b[2]*rn); ub.w = f2bf(b[3]*rn);
    u16* orow = xn + (size_t)row * DIM;
    *(ushort4*)(orow + 4*t)       = ua;
    *(ushort4*)(orow + 256 + 4*t) = ub;
}

// convert 8 fp32 -> short8 of bf16 (RNE); compiler emits native cvt (pk-pairable)
__device__ __forceinline__ short8 cvt_bf8(floatx4 a, floatx4 b) {
    union { short8 s8; u16 u[8]; } p;
#pragma unroll
    for (int j = 0; j < 4; ++j) p.u[j] = f2bf(a[j]);
#pragma unroll
    for (int j = 0; j < 4; ++j) p.u[4 + j] = f2bf(b[j]);
    return p.s8;
}

// ---------------- Kernel 2: A-stationary persistent GEMM ----------------
// 256 blocks = 4 M-groups (128 rows each) x 64 tile-streams.
// Per block: A slice (128x512 bf16) pinned in swizzled LDS; W fp32 streamed
// global->reg->bf16->MFMA B-frag (depth-2 pipeline). No barriers in main loop.
// 8 waves: wave = (mhalf = w&1)*64 rows x (nslot = w>>1)*64 cols of the
// 128x256 block tile. MFMA 32x32x16: A row=lane&31,k=(lane>>5)*8+j;
// C/D col=lane&31, row=(reg&3)+8*(reg>>2)+4*(lane>>5)  [m74/m101-verified].
__global__ __launch_bounds__(512, 1) void arcface_main(
        const float* __restrict__ w, const u16* __restrict__ xn,
        float* __restrict__ partials) {
    __shared__ __align__(16) u16 ash[128 * 512];   // 128 KB swizzled A
    __shared__ float pacc[8][64];                  // cross-wave row-sum buffer

    const int t = threadIdx.x;
    const int bid = blockIdx.x;
    const int stream = bid & 63;
    const int mgrp = bid >> 6;       // 0..3
    const int wv = t >> 6;
    const int lane = t & 63;
    const int l31 = lane & 31;
    const int hi = lane >> 5;
    const int mhalf = wv & 1;
    const int nslot = wv >> 1;

    // ---- one-time: stage A slice into LDS (16B-granule XOR swizzle) ----
    {
        const u16* xbase = xn + (size_t)(mgrp * 128) * DIM;
#pragma unroll
        for (int i = 0; i < 16; ++i) {
            const int gid = t + i * 512;
            const int row = gid >> 6;          // 0..127
            const int g = gid & 63;            // 16B granule in row
            floatx4 v = *(const floatx4*)(xbase + (size_t)row * DIM + g * 8);
            *(floatx4*)(&ash[row * DIM + ((g ^ (row & 7)) * 8)]) = v;
        }
    }
    __syncthreads();

    float run[2][16];
#pragma unroll
    for (int mf = 0; mf < 2; ++mf)
#pragma unroll
        for (int r = 0; r < 16; ++r) run[mf][r] = 0.f;

    const int arow0 = (mhalf * 64 + l31) * DIM;
    const int arow1 = (mhalf * 64 + 32 + l31) * DIM;

    for (int tile = stream; tile < NT; tile += NSTREAM) {
        const int c0 = tile * BNB + nslot * 64;
        bool vfrag[2];
        const float* wp[2];
#pragma unroll
        for (int ni = 0; ni < 2; ++ni) {
            const int c = c0 + ni * 32 + l31;
            vfrag[ni] = (c0 + ni * 32) < NCLASS;      // frags are never partial
            const int cc = min(c, NCLASS - 1);
            wp[ni] = w + (size_t)cc * DIM + hi * 8;
        }

        floatx16 acc[2][2];
#pragma unroll
        for (int mf = 0; mf < 2; ++mf)
#pragma unroll
            for (int ni = 0; ni < 2; ++ni) acc[mf][ni] = (floatx16)0.0f;

        float ssq[2] = {0.f, 0.f};
        floatx4 pb[2][2][2];   // [slot][ni][pair] in-flight W fp32
#pragma unroll
        for (int ni = 0; ni < 2; ++ni) {
            pb[0][ni][0] = *(const floatx4*)(wp[ni]);
            pb[0][ni][1] = *(const floatx4*)(wp[ni] + 4);
            pb[1][ni][0] = *(const floatx4*)(wp[ni] + 16);
            pb[1][ni][1] = *(const floatx4*)(wp[ni] + 20);
        }

#pragma unroll
        for (int ks = 0; ks < 32; ++ks) {
            const int sl = ks & 1;
            short8 bfr[2];
#pragma unroll
            for (int ni = 0; ni < 2; ++ni) {
                floatx4 lo = pb[sl][ni][0], hp = pb[sl][ni][1];
                ssq[ni] += lo[0]*lo[0] + lo[1]*lo[1] + lo[2]*lo[2] + lo[3]*lo[3]
                         + hp[0]*hp[0] + hp[1]*hp[1] + hp[2]*hp[2] + hp[3]*hp[3];
                bfr[ni] = cvt_bf8(lo, hp);
            }
            if (ks < 30) {
#pragma unroll
                for (int ni = 0; ni < 2; ++ni) {
                    pb[sl][ni][0] = *(const floatx4*)(wp[ni] + (ks + 2) * 16);
                    pb[sl][ni][1] = *(const floatx4*)(wp[ni] + (ks + 2) * 16 + 4);
                }
            }
            const int gp = ((2 * ks + hi) ^ (l31 & 7)) * 8;
            short8 a0 = *(const short8*)(&ash[arow0 + gp]);
            short8 a1 = *(const short8*)(&ash[arow1 + gp]);
            acc[0][0] = __builtin_amdgcn_mfma_f32_32x32x16_bf16(a0, bfr[0], acc[0][0], 0, 0, 0);
            acc[0][1] = __builtin_amdgcn_mfma_f32_32x32x16_bf16(a0, bfr[1], acc[0][1], 0, 0, 0);
            acc[1][0] = __builtin_amdgcn_mfma_f32_32x32x16_bf16(a1, bfr[0], acc[1][0], 0, 0, 0);
            acc[1][1] = __builtin_amdgcn_mfma_f32_32x32x16_bf16(a1, bfr[1], acc[1][1], 0, 0, 0);
        }

        // ---- epilogue: column 1/||w||, exp accumulate into running sums ----
        ssq[0] += __shfl_xor(ssq[0], 32);
        ssq[1] += __shfl_xor(ssq[1], 32);
#pragma unroll
        for (int ni = 0; ni < 2; ++ni) {
            if (!vfrag[ni]) continue;
            const float sa = S_SCALE * (1.0f / fmaxf(sqrtf(ssq[ni]), 1e-12f)) * LOG2E;
            const float sb = -S_SCALE * LOG2E;
#pragma unroll
            for (int mf = 0; mf < 2; ++mf)
#pragma unroll
                for (int r = 0; r < 16; ++r)
                    run[mf][r] += exp2f(fmaf(acc[mf][ni][r], sa, sb));
        }
    }

    // ---- block-level row reduction and single partials write ----
#pragma unroll
    for (int mf = 0; mf < 2; ++mf)
#pragma unroll
        for (int r = 0; r < 16; ++r) {
            float s = run[mf][r];
            s += __shfl_xor(s, 1);
            s += __shfl_xor(s, 2);
            s += __shfl_xor(s, 4);
            s += __shfl_xor(s, 8);
            s += __shfl_xor(s, 16);
            if (l31 == 0)
                pacc[wv][mf * 32 + (r & 3) + 8 * (r >> 2) + 4 * hi] = s;
        }
    __syncthreads();
    if (t < 128) {
        const int h = t >> 6, r64 = t & 63;
        const float s = pacc[h][r64] + pacc[h + 2][r64] + pacc[h + 4][r64] + pacc[h + 6][r64];
        partials[(size_t)stream * BATCH + mgrp * 128 + t] = s;
    }
}

// ---------------- Kernel 3a: LSE + exact target term + nll ----------------
__global__ void reduce_lse(const float* __restrict__ partials,
                           const float* __restrict__ w,
                           const u16* __restrict__ xn,
                           const int* __restrict__ target,
                           float* __restrict__ nll) {
    const int m = blockIdx.x;
    const int t = threadIdx.x; // 64 = 1 wave
    float tot = partials[(size_t)t * BATCH + m];
#pragma unroll
    for (int d = 1; d < 64; d <<= 1) tot += __shfl_xor(tot, d);

    const int tg = target[m];
    const float* wr = w + (size_t)tg * DIM + t * 8;
    floatx4 w0 = *(const floatx4*)(wr);
    floatx4 w1 = *(const floatx4*)(wr + 4);
    short8 xv = *(const short8*)(xn + (size_t)m * DIM + t * 8);
    float dot = 0.f, ssq = 0.f;
#pragma unroll
    for (int j = 0; j < 4; ++j) {
        ssq += w0[j] * w0[j];
        dot += bf2f((u16)xv[j]) * bf2f(f2bf(w0[j]));   // same bf16 values as MFMA path
    }
#pragma unroll
    for (int j = 0; j < 4; ++j) {
        ssq += w1[j] * w1[j];
        dot += bf2f((u16)xv[4 + j]) * bf2f(f2bf(w1[j]));
    }
#pragma unroll
    for (int d = 1; d < 64; d <<= 1) {
        dot += __shfl_xor(dot, d);
        ssq += __shfl_xor(ssq, d);
    }
    if (t == 0) {
        const float rs = 1.0f / fmaxf(sqrtf(ssq), 1e-12f);
        const float cosv = dot * rs;
        const float sine = sqrtf(fmaxf(1.f - cosv * cosv, 0.f));
        float phi = cosv * COSM - sine * SINM;
        if (!(cosv > 0.f)) phi = cosv;                 // easy_margin
        const float lgp = S_SCALE * phi, lgc = S_SCALE * cosv;
        // main loop summed the target col as a plain class: swap it for phi
        const float tt = tot - __expf(lgc - S_SCALE) + __expf(lgp - S_SCALE);
        nll[m] = (logf(fmaxf(tt, 1e-30f)) + S_SCALE) - lgp;
    }
}

// ---------------- Kernel 3b: mean ----------------
__global__ void reduce_mean(const float* __restrict__ nll, float* __restrict__ out) {
    const int t = threadIdx.x; // 512
    float s = nll[t];
#pragma unroll
    for (int d = 1; d < 64; d <<= 1) s += __shfl_xor(s, d);
    __shared__ float red[8];
    if ((t & 63) == 0) red[t >> 6] = s;
    __syncthreads();
    if (t == 0) {
        float tot = 0.f;
#pragma unroll
        for (int i = 0; i < 8; ++i) tot += red[i];
        out[0] = tot / (float)BATCH;
    }
}

extern "C" void kernel_launch(void* const* d_in, const int* in_sizes, int n_in,
                              void* d_out, int out_size, void* d_ws, size_t ws_size,
                              hipStream_t stream) {
    const float* x = (const float*)d_in[0];
    const float* w = (const float*)d_in[1];
    const int* target = (const int*)d_in[2];

    char* ws = (char*)d_ws;
    u16* xn        = (u16*)ws;
    float* partials= (float*)(ws + 524288);
    float* nll     = (float*)(ws + 655360);

    xnorm_kernel<<<BATCH, 64, 0, stream>>>(x, xn);
    arcface_main<<<GRID, 512, 0, stream>>>(w, xn, partials);
    reduce_lse<<<BATCH, 64, 0, stream>>>(partials, w, xn, target, nll);
    reduce_mean<<<1, 512, 0, stream>>>(nll, (float*)d_out);
}